// Round 5
// baseline (380.241 us; speedup 1.0000x reference)
//
#include <hip/hip_runtime.h>
#include <hip/hip_bf16.h>
#include <math.h>

#define BB   16      // batch
#define NC   1024    // candidates per query row
#define QL   32      // query tokens
#define HD   128     // embed dim
#define DLN  64      // doc tokens per doc
#define RK   128     // rescore set size per row (pow2, >= k=100 with margin)
#define NPW  4       // candidates per wave in the screen kernel

typedef __attribute__((ext_vector_type(8))) short bf16x8;  // 8 bf16 (4 VGPRs)
typedef __attribute__((ext_vector_type(4))) float f32x4;   // MFMA accumulator

// ---------------------------------------------------------------------------
// K0: precompute q planes: bf16(q) for the MFMA screen, f64(q) for rescore.
// ---------------------------------------------------------------------------
__global__ __launch_bounds__(256) void k_qprep(
    const float* __restrict__ q, unsigned short* __restrict__ qhi,
    double* __restrict__ qf64)
{
    int i = blockIdx.x * 256 + threadIdx.x;          // BB*QL*HD = 65536
    float v = q[i];
    __hip_bfloat16 h = __float2bfloat16(v);
    qhi[i]  = *reinterpret_cast<unsigned short*>(&h);
    qf64[i] = (double)v;
}

// ---------------------------------------------------------------------------
// K1: pids = emb2pid[topk]; validate; per-row descending bitonic sort; dedup.
// ---------------------------------------------------------------------------
__global__ __launch_bounds__(1024) void k_gather_sort_dedup(
    const int* __restrict__ topk, const int* __restrict__ emb2pid,
    int n_emb, int n_docs, int* __restrict__ pids_out)
{
    const int b = blockIdx.x;
    const int t = threadIdx.x;
    __shared__ int s[NC];

    int idx = topk[b * NC + t];
    int pid = (idx >= 0 && idx < n_emb) ? emb2pid[idx] : -1;
    if (pid < 0 || pid >= n_docs) pid = -1;
    s[t] = pid;
    __syncthreads();

    for (int k2 = 2; k2 <= NC; k2 <<= 1) {
        for (int j = k2 >> 1; j > 0; j >>= 1) {
            int ixj = t ^ j;
            if (ixj > t) {
                int a = s[t], c = s[ixj];
                bool desc = ((t & k2) == 0);
                if (desc ? (a < c) : (a > c)) { s[t] = c; s[ixj] = a; }
            }
            __syncthreads();
        }
    }
    int v = s[t];
    pids_out[b * NC + t] = (t > 0 && v == s[t - 1]) ? -1 : v;
}

// ---------------------------------------------------------------------------
// Round 8 f32 to bf16 (RNE) -> one bf16x8 fragment.
// ---------------------------------------------------------------------------
__device__ __forceinline__ bf16x8 cvt8(float4 a, float4 c)
{
    float v[8] = {a.x, a.y, a.z, a.w, c.x, c.y, c.z, c.w};
    bf16x8 r;
#pragma unroll
    for (int j = 0; j < 8; ++j) {
        __hip_bfloat16 h = __float2bfloat16(v[j]);
        r[j] = *reinterpret_cast<short*>(&h);
    }
    return r;
}

// ---------------------------------------------------------------------------
// K2: MFMA screening (R3 structure, proven). One wave per NPW candidates.
// S[32q][64d] ~= bf16(q) . bf16(doc)^T via mfma_f32_16x16x32_bf16, register-
// direct doc loads, no LDS, no barriers. Screen-only accuracy (~3e-3 std)
// is restored by the exact f64 rescore of the selected top-RK.
//   A/B frag: lane holds 8 contig k at row/col = lane&15, kblock = lane>>4
//   C/D:      col = lane&15 (doc row in tile), row = (lane>>4)*4 + reg (q row)
// ---------------------------------------------------------------------------
__global__ __launch_bounds__(256) void k_screen_mfma(
    const unsigned short* __restrict__ qhi,  // [BB][QL][HD] bf16(q)
    const float* __restrict__ vecs,          // [n_docs][DLN][HD] f32
    const int* __restrict__ pids,            // [BB][NC]
    float* __restrict__ scores)              // [BB][NC]
{
    const int lane = threadIdx.x & 63;
    const int wv   = threadIdx.x >> 6;              // 0..3
    const int bk   = blockIdx.x;                    // 0..1023
    const int b    = bk >> 6;                       // 64 blocks per batch row
    const int nb   = (bk & 63) * (4 * NPW) + wv * NPW;

    const int r16 = lane & 15;
    const int kb  = lane >> 4;

    // A fragments: direct bf16 loads (R4-proven offsets).
    bf16x8 qf[2][4];
#pragma unroll
    for (int m = 0; m < 2; ++m)
#pragma unroll
        for (int ks = 0; ks < 4; ++ks) {
            int off = ((b * QL + m * 16 + r16) * HD + ks * 32 + kb * 8);
            qf[m][ks] = *(const bf16x8*)(qhi + off);
        }

    for (int nn = 0; nn < NPW; ++nn) {
        const int n = nb + nn;
        const int pid = pids[b * NC + n];
        if (pid < 0) {
            if (lane == 0) scores[b * NC + n] = -__builtin_inff();
            continue;
        }
        const float* dbase = vecs + (size_t)pid * (DLN * HD);

        f32x4 acc[2][4] = {};
#pragma unroll
        for (int ks = 0; ks < 4; ++ks) {
#pragma unroll
            for (int nt = 0; nt < 4; ++nt) {
                const float* p = dbase + (nt * 16 + r16) * HD + ks * 32 + kb * 8;
                float4 x0 = *(const float4*)p;
                float4 x1 = *(const float4*)(p + 4);
                bf16x8 bh = cvt8(x0, x1);
#pragma unroll
                for (int m = 0; m < 2; ++m)
                    acc[m][nt] = __builtin_amdgcn_mfma_f32_16x16x32_bf16(
                        qf[m][ks], bh, acc[m][nt], 0, 0, 0);
            }
        }

        // Max over d: elementwise over the 4 n-tiles, then over lanes l&15.
        float s = 0.f;
#pragma unroll
        for (int m = 0; m < 2; ++m) {
#pragma unroll
            for (int r = 0; r < 4; ++r) {
                float x = fmaxf(fmaxf(acc[m][0][r], acc[m][1][r]),
                                fmaxf(acc[m][2][r], acc[m][3][r]));
                x = fmaxf(x, __shfl_xor(x, 1));
                x = fmaxf(x, __shfl_xor(x, 2));
                x = fmaxf(x, __shfl_xor(x, 4));
                x = fmaxf(x, __shfl_xor(x, 8));
                s += x;                              // row-max for q=(m*16+kb*4+r)
            }
        }
        // Sum over the 4 kb-groups -> all 32 q rows.
        s += __shfl_xor(s, 16);
        s += __shfl_xor(s, 32);
        if (lane == 0) scores[b * NC + n] = s * (1.0f / 32.0f);
    }
}

// ---------------------------------------------------------------------------
// K3a: per-row full bitonic sort of (f32 score desc, idx asc); keep top RK.
// ---------------------------------------------------------------------------
__global__ __launch_bounds__(1024) void k_select(
    const float* __restrict__ scores, int* __restrict__ sel)
{
    const int b = blockIdx.x;
    const int t = threadIdx.x;
    __shared__ float ss[NC];
    __shared__ int   si[NC];

    ss[t] = scores[b * NC + t];
    si[t] = t;
    __syncthreads();

    for (int k2 = 2; k2 <= NC; k2 <<= 1) {
        for (int j = k2 >> 1; j > 0; j >>= 1) {
            int ixj = t ^ j;
            if (ixj > t) {
                float as = ss[t], bs = ss[ixj];
                int   ai = si[t], bi = si[ixj];
                bool a_first = (as > bs) || (as == bs && ai < bi);
                bool desc = ((t & k2) == 0);
                if (desc ? !a_first : a_first) { ss[t] = bs; si[t] = bi; ss[ixj] = as; si[ixj] = ai; }
            }
            __syncthreads();
        }
    }
    if (t < RK) sel[b * RK + t] = si[t];
}

// ---------------------------------------------------------------------------
// K3b: exact f64 rescore of the RK selected per row (R4-proven structure);
// q loaded directly as f64 (values identical to (double)f32 -> bit-exact).
// Thread map: tq=t&15 -> q rows {2tq,2tq+1}; tdw=t>>4 -> d rows {2tdw,2tdw+1}
// within each 32-row chunk.
// ---------------------------------------------------------------------------
#define CPAD (HD + 4)

__global__ __launch_bounds__(256) void k_rescore_f64(
    const double* __restrict__ qf64, // [BB][QL][HD] f64
    const float* __restrict__ vecs,  // [n_docs][DLN][HD]
    const int* __restrict__ pids,    // [BB][NC]
    const int* __restrict__ sel,     // [BB][RK]
    double* __restrict__ resc)       // [BB][RK]
{
    const int r = blockIdx.x, b = blockIdx.y;
    const int t = threadIdx.x;
    const int n = sel[b * RK + r];
    const int pid = pids[b * NC + n];
    if (pid < 0) {
        if (t == 0) resc[b * RK + r] = -__builtin_inf();
        return;
    }

    __shared__ float sdoc[32][CPAD];
    __shared__ double red[4][16][2];

    const int tq  = t & 15;
    const int tdw = t >> 4;                  // 0..15
    const double* qb = qf64 + ((size_t)b * QL + tq * 2) * HD;

    double m0 = -__builtin_inf(), m1 = -__builtin_inf();

    for (int c = 0; c < 2; ++c) {
        __syncthreads();                     // protect previous chunk reads
        {
            const float4* src = (const float4*)(vecs + ((size_t)pid * DLN + c * 32) * HD);
            for (int i = t; i < 32 * HD / 4; i += 256) {
                float4 v = src[i];
                int d = i >> 5, h4 = (i & 31) << 2;
                *(float4*)&sdoc[d][h4] = v;
            }
        }
        __syncthreads();

        const int d0 = tdw * 2;
        double a00 = 0.0, a01 = 0.0, a10 = 0.0, a11 = 0.0;
        for (int h = 0; h < HD; h += 4) {
            double4 qa = *(const double4*)(qb + h);
            double4 qc = *(const double4*)(qb + HD + h);
            float4 b0 = *(const float4*)&sdoc[d0][h];
            float4 b1 = *(const float4*)&sdoc[d0 + 1][h];
            a00 += qa.x * b0.x + qa.y * b0.y + qa.z * b0.z + qa.w * b0.w;
            a01 += qa.x * b1.x + qa.y * b1.y + qa.z * b1.z + qa.w * b1.w;
            a10 += qc.x * b0.x + qc.y * b0.y + qc.z * b0.z + qc.w * b0.w;
            a11 += qc.x * b1.x + qc.y * b1.y + qc.z * b1.z + qc.w * b1.w;
        }
        m0 = fmax(m0, fmax(a00, a01));
        m1 = fmax(m1, fmax(a10, a11));
    }

    // Max across the wave's tdw groups (lanes l, l^16, l^32, l^48 share tq).
    m0 = fmax(m0, __shfl_xor(m0, 16)); m1 = fmax(m1, __shfl_xor(m1, 16));
    m0 = fmax(m0, __shfl_xor(m0, 32)); m1 = fmax(m1, __shfl_xor(m1, 32));

    const int wave = t >> 6;
    if ((t & 63) < 16) { red[wave][tq][0] = m0; red[wave][tq][1] = m1; }
    __syncthreads();

    if (t < 32) {
        int g = t >> 1, i = t & 1;           // q row = 2g+i = t
        double v = fmax(fmax(red[0][g][i], red[1][g][i]),
                        fmax(red[2][g][i], red[3][g][i]));
        v += __shfl_xor(v, 1);
        v += __shfl_xor(v, 2);
        v += __shfl_xor(v, 4);
        v += __shfl_xor(v, 8);
        v += __shfl_xor(v, 16);
        if (t == 0) resc[b * RK + r] = v * (1.0 / 32.0);
    }
}

// ---------------------------------------------------------------------------
// K3c: sort the RK rescored candidates by (f64 score desc, idx asc); emit k.
// ---------------------------------------------------------------------------
__global__ __launch_bounds__(RK) void k_final(
    const double* __restrict__ resc, const int* __restrict__ sel,
    const int* __restrict__ pids, float* __restrict__ out, int k)
{
    const int b = blockIdx.x;
    const int t = threadIdx.x;
    __shared__ double ss[RK];
    __shared__ int    sn[RK];

    ss[t] = resc[b * RK + t];
    sn[t] = sel[b * RK + t];
    __syncthreads();

    for (int k2 = 2; k2 <= RK; k2 <<= 1) {
        for (int j = k2 >> 1; j > 0; j >>= 1) {
            int ixj = t ^ j;
            if (ixj > t) {
                double as = ss[t], bs = ss[ixj];
                int    ai = sn[t], bi = sn[ixj];
                bool a_first = (as > bs) || (as == bs && ai < bi);
                bool desc = ((t & k2) == 0);
                if (desc ? !a_first : a_first) { ss[t] = bs; sn[t] = bi; ss[ixj] = as; sn[ixj] = ai; }
            }
            __syncthreads();
        }
    }

    if (t < k) {
        out[b * k + t]          = (float)pids[b * NC + sn[t]];  // top_pids
        out[BB * k + b * k + t] = (float)ss[t];                 // top_scores
    }
}

// ---------------------------------------------------------------------------
extern "C" void kernel_launch(void* const* d_in, const int* in_sizes, int n_in,
                              void* d_out, int out_size, void* d_ws, size_t ws_size,
                              hipStream_t stream)
{
    const float* q_vectors = (const float*)d_in[0];   // [16][32][128] f32
    const int*   topk_idx  = (const int*)d_in[1];     // [16][1024] i32
    const float* vectors   = (const float*)d_in[2];   // [20000][64][128] f32
    const int*   emb2pid   = (const int*)d_in[3];     // [1280000] i32

    const int n_emb  = in_sizes[3];
    const int n_docs = in_sizes[2] / (DLN * HD);
    const int k      = out_size / (2 * BB);           // 100

    char* ws = (char*)d_ws;
    int*    pids_ws   = (int*)ws;      ws += BB * NC * sizeof(int);      // 64 KB
    float*  scores_ws = (float*)ws;    ws += BB * NC * sizeof(float);    // 64 KB
    int*    sel_ws    = (int*)ws;      ws += BB * RK * sizeof(int);      // 8 KB
    double* resc_ws   = (double*)ws;   ws += BB * RK * sizeof(double);   // 16 KB
    unsigned short* qhi_ws = (unsigned short*)ws; ws += BB * QL * HD * 2; // 128 KB
    double* qf64_ws   = (double*)ws;                                     // 512 KB

    k_qprep<<<dim3(BB * QL * HD / 256), dim3(256), 0, stream>>>(
        q_vectors, qhi_ws, qf64_ws);

    k_gather_sort_dedup<<<dim3(BB), dim3(NC), 0, stream>>>(
        topk_idx, emb2pid, n_emb, n_docs, pids_ws);

    k_screen_mfma<<<dim3(BB * NC / (4 * NPW)), dim3(256), 0, stream>>>(
        qhi_ws, vectors, pids_ws, scores_ws);

    k_select<<<dim3(BB), dim3(NC), 0, stream>>>(scores_ws, sel_ws);

    k_rescore_f64<<<dim3(RK, BB), dim3(256), 0, stream>>>(
        qf64_ws, vectors, pids_ws, sel_ws, resc_ws);

    k_final<<<dim3(BB), dim3(RK), 0, stream>>>(
        resc_ws, sel_ws, pids_ws, (float*)d_out, k);
}

// Round 6
// 219.297 us; speedup vs baseline: 1.7339x; 1.7339x over previous
//
#include <hip/hip_runtime.h>
#include <hip/hip_bf16.h>
#include <math.h>

#define BB   16      // batch
#define NC   1024    // candidates per query row
#define QL   32      // query tokens
#define HD   128     // embed dim
#define DLN  64      // doc tokens per doc
#define RK   128     // rescore set size per row (pow2, >= k=100 with margin)
#define NPW  4       // candidates per wave in the screen kernel

typedef __attribute__((ext_vector_type(8))) short bf16x8;  // 8 bf16 (4 VGPRs)
typedef __attribute__((ext_vector_type(4))) float f32x4;   // MFMA accumulator

// ---------------------------------------------------------------------------
// K0: precompute bf16(q) for the MFMA screen.
// ---------------------------------------------------------------------------
__global__ __launch_bounds__(256) void k_qprep(
    const float* __restrict__ q, unsigned short* __restrict__ qhi)
{
    int i = blockIdx.x * 256 + threadIdx.x;          // BB*QL*HD = 65536
    float v = q[i];
    __hip_bfloat16 h = __float2bfloat16(v);
    qhi[i] = *reinterpret_cast<unsigned short*>(&h);
}

// ---------------------------------------------------------------------------
// K1: pids = emb2pid[topk]; validate; per-row descending bitonic sort; dedup.
// ---------------------------------------------------------------------------
__global__ __launch_bounds__(1024) void k_gather_sort_dedup(
    const int* __restrict__ topk, const int* __restrict__ emb2pid,
    int n_emb, int n_docs, int* __restrict__ pids_out)
{
    const int b = blockIdx.x;
    const int t = threadIdx.x;
    __shared__ int s[NC];

    int idx = topk[b * NC + t];
    int pid = (idx >= 0 && idx < n_emb) ? emb2pid[idx] : -1;
    if (pid < 0 || pid >= n_docs) pid = -1;
    s[t] = pid;
    __syncthreads();

    for (int k2 = 2; k2 <= NC; k2 <<= 1) {
        for (int j = k2 >> 1; j > 0; j >>= 1) {
            int ixj = t ^ j;
            if (ixj > t) {
                int a = s[t], c = s[ixj];
                bool desc = ((t & k2) == 0);
                if (desc ? (a < c) : (a > c)) { s[t] = c; s[ixj] = a; }
            }
            __syncthreads();
        }
    }
    int v = s[t];
    pids_out[b * NC + t] = (t > 0 && v == s[t - 1]) ? -1 : v;
}

// ---------------------------------------------------------------------------
// Round 8 f32 to bf16 (RNE) -> one bf16x8 fragment.
// ---------------------------------------------------------------------------
__device__ __forceinline__ bf16x8 cvt8(float4 a, float4 c)
{
    float v[8] = {a.x, a.y, a.z, a.w, c.x, c.y, c.z, c.w};
    bf16x8 r;
#pragma unroll
    for (int j = 0; j < 8; ++j) {
        __hip_bfloat16 h = __float2bfloat16(v[j]);
        r[j] = *reinterpret_cast<short*>(&h);
    }
    return r;
}

// ---------------------------------------------------------------------------
// K2: MFMA screening (R5 version, kept). One wave per NPW candidates.
// S[32q][64d] ~= bf16(q) . bf16(doc)^T via mfma_f32_16x16x32_bf16, register-
// direct doc loads, no LDS, no barriers. Screen error (~3e-3 std) is fixed
// by the exact f64 rescore of the selected top-RK.
//   A/B frag: lane holds 8 contig k at row/col = lane&15, kblock = lane>>4
//   C/D:      col = lane&15 (doc row in tile), row = (lane>>4)*4 + reg (q row)
// ---------------------------------------------------------------------------
__global__ __launch_bounds__(256) void k_screen_mfma(
    const unsigned short* __restrict__ qhi,  // [BB][QL][HD] bf16(q)
    const float* __restrict__ vecs,          // [n_docs][DLN][HD] f32
    const int* __restrict__ pids,            // [BB][NC]
    float* __restrict__ scores)              // [BB][NC]
{
    const int lane = threadIdx.x & 63;
    const int wv   = threadIdx.x >> 6;              // 0..3
    const int bk   = blockIdx.x;                    // 0..1023
    const int b    = bk >> 6;                       // 64 blocks per batch row
    const int nb   = (bk & 63) * (4 * NPW) + wv * NPW;

    const int r16 = lane & 15;
    const int kb  = lane >> 4;

    // A fragments: direct bf16 loads.
    bf16x8 qf[2][4];
#pragma unroll
    for (int m = 0; m < 2; ++m)
#pragma unroll
        for (int ks = 0; ks < 4; ++ks) {
            int off = ((b * QL + m * 16 + r16) * HD + ks * 32 + kb * 8);
            qf[m][ks] = *(const bf16x8*)(qhi + off);
        }

    for (int nn = 0; nn < NPW; ++nn) {
        const int n = nb + nn;
        const int pid = pids[b * NC + n];
        if (pid < 0) {
            if (lane == 0) scores[b * NC + n] = -__builtin_inff();
            continue;
        }
        const float* dbase = vecs + (size_t)pid * (DLN * HD);

        f32x4 acc[2][4] = {};
#pragma unroll
        for (int ks = 0; ks < 4; ++ks) {
#pragma unroll
            for (int nt = 0; nt < 4; ++nt) {
                const float* p = dbase + (nt * 16 + r16) * HD + ks * 32 + kb * 8;
                float4 x0 = *(const float4*)p;
                float4 x1 = *(const float4*)(p + 4);
                bf16x8 bh = cvt8(x0, x1);
#pragma unroll
                for (int m = 0; m < 2; ++m)
                    acc[m][nt] = __builtin_amdgcn_mfma_f32_16x16x32_bf16(
                        qf[m][ks], bh, acc[m][nt], 0, 0, 0);
            }
        }

        // Max over d: elementwise over the 4 n-tiles, then over lanes l&15.
        float s = 0.f;
#pragma unroll
        for (int m = 0; m < 2; ++m) {
#pragma unroll
            for (int r = 0; r < 4; ++r) {
                float x = fmaxf(fmaxf(acc[m][0][r], acc[m][1][r]),
                                fmaxf(acc[m][2][r], acc[m][3][r]));
                x = fmaxf(x, __shfl_xor(x, 1));
                x = fmaxf(x, __shfl_xor(x, 2));
                x = fmaxf(x, __shfl_xor(x, 4));
                x = fmaxf(x, __shfl_xor(x, 8));
                s += x;                              // row-max for q=(m*16+kb*4+r)
            }
        }
        // Sum over the 4 kb-groups -> all 32 q rows.
        s += __shfl_xor(s, 16);
        s += __shfl_xor(s, 32);
        if (lane == 0) scores[b * NC + n] = s * (1.0f / 32.0f);
    }
}

// ---------------------------------------------------------------------------
// K3a: per-row full bitonic sort of (f32 score desc, idx asc); keep top RK.
// ---------------------------------------------------------------------------
__global__ __launch_bounds__(1024) void k_select(
    const float* __restrict__ scores, int* __restrict__ sel)
{
    const int b = blockIdx.x;
    const int t = threadIdx.x;
    __shared__ float ss[NC];
    __shared__ int   si[NC];

    ss[t] = scores[b * NC + t];
    si[t] = t;
    __syncthreads();

    for (int k2 = 2; k2 <= NC; k2 <<= 1) {
        for (int j = k2 >> 1; j > 0; j >>= 1) {
            int ixj = t ^ j;
            if (ixj > t) {
                float as = ss[t], bs = ss[ixj];
                int   ai = si[t], bi = si[ixj];
                bool a_first = (as > bs) || (as == bs && ai < bi);
                bool desc = ((t & k2) == 0);
                if (desc ? !a_first : a_first) { ss[t] = bs; si[t] = bi; ss[ixj] = as; si[ixj] = ai; }
            }
            __syncthreads();
        }
    }
    if (t < RK) sel[b * RK + t] = si[t];
}

// ---------------------------------------------------------------------------
// K3b: exact f64 rescore of the RK selected per row — R1-proven kernel
// verbatim (one-chunk 64-row LDS tile, f32 q loads, f64 accumulate). This
// exact structure bit-matched the np reference and ran ~72 us at this grid.
// ---------------------------------------------------------------------------
#define DPAD (HD + 4)

__global__ __launch_bounds__(256) void k_rescore_f64(
    const float* __restrict__ q,     // [BB][QL][HD]
    const float* __restrict__ vecs,  // [n_docs][DLN][HD]
    const int* __restrict__ pids,    // [BB][NC]
    const int* __restrict__ sel,     // [BB][RK]
    double* __restrict__ resc)       // [BB][RK]
{
    const int r = blockIdx.x, b = blockIdx.y;
    const int t = threadIdx.x;
    const int n = sel[b * RK + r];
    const int pid = pids[b * NC + n];
    if (pid < 0) {
        if (t == 0) resc[b * RK + r] = -__builtin_inf();
        return;
    }

    __shared__ float sdoc[DLN][DPAD];
    __shared__ double red[4][16][2];

    {
        const float4* src = (const float4*)(vecs + (size_t)pid * DLN * HD);
        for (int i = t; i < DLN * HD / 4; i += 256) {
            float4 v = src[i];
            int d  = i >> 5;
            int h4 = (i & 31) << 2;
            *(float4*)&sdoc[d][h4] = v;
        }
    }
    __syncthreads();

    const int tq = t & 15;
    const int td = t >> 4;
    const float* qb = q + ((size_t)b * QL + tq * 2) * HD;

    double acc[2][4] = {};
    for (int h = 0; h < HD; h += 4) {
        float4 a0 = *(const float4*)(qb + h);
        float4 a1 = *(const float4*)(qb + HD + h);
        float4 bv[4];
#pragma unroll
        for (int j = 0; j < 4; ++j)
            bv[j] = *(const float4*)&sdoc[td * 4 + j][h];
#pragma unroll
        for (int j = 0; j < 4; ++j) {
            acc[0][j] += (double)a0.x * bv[j].x + (double)a0.y * bv[j].y
                       + (double)a0.z * bv[j].z + (double)a0.w * bv[j].w;
            acc[1][j] += (double)a1.x * bv[j].x + (double)a1.y * bv[j].y
                       + (double)a1.z * bv[j].z + (double)a1.w * bv[j].w;
        }
    }

    double m0 = fmax(fmax(acc[0][0], acc[0][1]), fmax(acc[0][2], acc[0][3]));
    double m1 = fmax(fmax(acc[1][0], acc[1][1]), fmax(acc[1][2], acc[1][3]));

    m0 = fmax(m0, __shfl_xor(m0, 16)); m1 = fmax(m1, __shfl_xor(m1, 16));
    m0 = fmax(m0, __shfl_xor(m0, 32)); m1 = fmax(m1, __shfl_xor(m1, 32));

    const int wave = t >> 6;
    if ((t & 63) < 16) { red[wave][tq][0] = m0; red[wave][tq][1] = m1; }
    __syncthreads();

    if (t < 32) {
        int g = t >> 1, i = t & 1;
        double v = fmax(fmax(red[0][g][i], red[1][g][i]),
                        fmax(red[2][g][i], red[3][g][i]));
        v += __shfl_xor(v, 1);
        v += __shfl_xor(v, 2);
        v += __shfl_xor(v, 4);
        v += __shfl_xor(v, 8);
        v += __shfl_xor(v, 16);
        if (t == 0) resc[b * RK + r] = v * (1.0 / 32.0);
    }
}

// ---------------------------------------------------------------------------
// K3c: sort the RK rescored candidates by (f64 score desc, idx asc); emit k.
// ---------------------------------------------------------------------------
__global__ __launch_bounds__(RK) void k_final(
    const double* __restrict__ resc, const int* __restrict__ sel,
    const int* __restrict__ pids, float* __restrict__ out, int k)
{
    const int b = blockIdx.x;
    const int t = threadIdx.x;
    __shared__ double ss[RK];
    __shared__ int    sn[RK];

    ss[t] = resc[b * RK + t];
    sn[t] = sel[b * RK + t];
    __syncthreads();

    for (int k2 = 2; k2 <= RK; k2 <<= 1) {
        for (int j = k2 >> 1; j > 0; j >>= 1) {
            int ixj = t ^ j;
            if (ixj > t) {
                double as = ss[t], bs = ss[ixj];
                int    ai = sn[t], bi = sn[ixj];
                bool a_first = (as > bs) || (as == bs && ai < bi);
                bool desc = ((t & k2) == 0);
                if (desc ? !a_first : a_first) { ss[t] = bs; sn[t] = bi; ss[ixj] = as; sn[ixj] = ai; }
            }
            __syncthreads();
        }
    }

    if (t < k) {
        out[b * k + t]          = (float)pids[b * NC + sn[t]];  // top_pids
        out[BB * k + b * k + t] = (float)ss[t];                 // top_scores
    }
}

// ---------------------------------------------------------------------------
extern "C" void kernel_launch(void* const* d_in, const int* in_sizes, int n_in,
                              void* d_out, int out_size, void* d_ws, size_t ws_size,
                              hipStream_t stream)
{
    const float* q_vectors = (const float*)d_in[0];   // [16][32][128] f32
    const int*   topk_idx  = (const int*)d_in[1];     // [16][1024] i32
    const float* vectors   = (const float*)d_in[2];   // [20000][64][128] f32
    const int*   emb2pid   = (const int*)d_in[3];     // [1280000] i32

    const int n_emb  = in_sizes[3];
    const int n_docs = in_sizes[2] / (DLN * HD);
    const int k      = out_size / (2 * BB);           // 100

    char* ws = (char*)d_ws;
    int*    pids_ws   = (int*)ws;      ws += BB * NC * sizeof(int);      // 64 KB
    float*  scores_ws = (float*)ws;    ws += BB * NC * sizeof(float);    // 64 KB
    int*    sel_ws    = (int*)ws;      ws += BB * RK * sizeof(int);      // 8 KB
    double* resc_ws   = (double*)ws;   ws += BB * RK * sizeof(double);   // 16 KB
    unsigned short* qhi_ws = (unsigned short*)ws;                        // 128 KB

    k_qprep<<<dim3(BB * QL * HD / 256), dim3(256), 0, stream>>>(
        q_vectors, qhi_ws);

    k_gather_sort_dedup<<<dim3(BB), dim3(NC), 0, stream>>>(
        topk_idx, emb2pid, n_emb, n_docs, pids_ws);

    k_screen_mfma<<<dim3(BB * NC / (4 * NPW)), dim3(256), 0, stream>>>(
        qhi_ws, vectors, pids_ws, scores_ws);

    k_select<<<dim3(BB), dim3(NC), 0, stream>>>(scores_ws, sel_ws);

    k_rescore_f64<<<dim3(RK, BB), dim3(256), 0, stream>>>(
        q_vectors, vectors, pids_ws, sel_ws, resc_ws);

    k_final<<<dim3(BB), dim3(RK), 0, stream>>>(
        resc_ws, sel_ws, pids_ws, (float*)d_out, k);
}

// Round 7
// 197.408 us; speedup vs baseline: 1.9262x; 1.1109x over previous
//
#include <hip/hip_runtime.h>
#include <hip/hip_bf16.h>
#include <math.h>

#define BB   16      // batch
#define NC   1024    // candidates per query row
#define QL   32      // query tokens
#define HD   128     // embed dim
#define DLN  64      // doc tokens per doc
#define RK   128     // rescore set size per row (pow2, >= k=100 with margin)
#define NPW  2       // candidates per wave in the screen kernel

typedef __attribute__((ext_vector_type(8))) short bf16x8;  // 8 bf16 (4 VGPRs)
typedef __attribute__((ext_vector_type(4))) float f32x4;   // MFMA accumulator

// ---------------------------------------------------------------------------
// K0: precompute bf16(q) for the MFMA screen.
// ---------------------------------------------------------------------------
__global__ __launch_bounds__(256) void k_qprep(
    const float* __restrict__ q, unsigned short* __restrict__ qhi)
{
    int i = blockIdx.x * 256 + threadIdx.x;          // BB*QL*HD = 65536
    float v = q[i];
    __hip_bfloat16 h = __float2bfloat16(v);
    qhi[i] = *reinterpret_cast<unsigned short*>(&h);
}

// ---------------------------------------------------------------------------
// K1: pids = emb2pid[topk]; validate; per-row descending bitonic sort; dedup.
// ---------------------------------------------------------------------------
__global__ __launch_bounds__(1024) void k_gather_sort_dedup(
    const int* __restrict__ topk, const int* __restrict__ emb2pid,
    int n_emb, int n_docs, int* __restrict__ pids_out)
{
    const int b = blockIdx.x;
    const int t = threadIdx.x;
    __shared__ int s[NC];

    int idx = topk[b * NC + t];
    int pid = (idx >= 0 && idx < n_emb) ? emb2pid[idx] : -1;
    if (pid < 0 || pid >= n_docs) pid = -1;
    s[t] = pid;
    __syncthreads();

    for (int k2 = 2; k2 <= NC; k2 <<= 1) {
        for (int j = k2 >> 1; j > 0; j >>= 1) {
            int ixj = t ^ j;
            if (ixj > t) {
                int a = s[t], c = s[ixj];
                bool desc = ((t & k2) == 0);
                if (desc ? (a < c) : (a > c)) { s[t] = c; s[ixj] = a; }
            }
            __syncthreads();
        }
    }
    int v = s[t];
    pids_out[b * NC + t] = (t > 0 && v == s[t - 1]) ? -1 : v;
}

// ---------------------------------------------------------------------------
// Round 8 f32 to bf16 (RNE) -> one bf16x8 fragment.
// ---------------------------------------------------------------------------
__device__ __forceinline__ bf16x8 cvt8(float4 a, float4 c)
{
    float v[8] = {a.x, a.y, a.z, a.w, c.x, c.y, c.z, c.w};
    bf16x8 r;
#pragma unroll
    for (int j = 0; j < 8; ++j) {
        __hip_bfloat16 h = __float2bfloat16(v[j]);
        r[j] = *reinterpret_cast<short*>(&h);
    }
    return r;
}

// ---------------------------------------------------------------------------
// K2: MFMA screening. One wave per NPW candidates; register-direct doc loads,
// no LDS, no barriers. __launch_bounds__(256,4): cap VGPR at 128 so we get
// 4 waves/SIMD (16 waves/CU) — R6 evidence says this kernel was occupancy-
// starved (VGPR-bloated load hoisting), not issue-bound.
//   A/B frag: lane holds 8 contig k at row/col = lane&15, kblock = lane>>4
//   C/D:      col = lane&15 (doc row in tile), row = (lane>>4)*4 + reg (q row)
// ---------------------------------------------------------------------------
__global__ __launch_bounds__(256, 4) void k_screen_mfma(
    const unsigned short* __restrict__ qhi,  // [BB][QL][HD] bf16(q)
    const float* __restrict__ vecs,          // [n_docs][DLN][HD] f32
    const int* __restrict__ pids,            // [BB][NC]
    float* __restrict__ scores)              // [BB][NC]
{
    const int lane = threadIdx.x & 63;
    const int wv   = threadIdx.x >> 6;              // 0..3
    const int bk   = blockIdx.x;
    const int BPR  = NC / (4 * NPW);                // blocks per batch row
    const int b    = bk / BPR;
    const int nb   = (bk % BPR) * (4 * NPW) + wv * NPW;

    const int r16 = lane & 15;
    const int kb  = lane >> 4;

    // A fragments: direct bf16 loads.
    bf16x8 qf[2][4];
#pragma unroll
    for (int m = 0; m < 2; ++m)
#pragma unroll
        for (int ks = 0; ks < 4; ++ks) {
            int off = ((b * QL + m * 16 + r16) * HD + ks * 32 + kb * 8);
            qf[m][ks] = *(const bf16x8*)(qhi + off);
        }

    for (int nn = 0; nn < NPW; ++nn) {
        const int n = nb + nn;
        const int pid = pids[b * NC + n];
        if (pid < 0) {
            if (lane == 0) scores[b * NC + n] = -__builtin_inff();
            continue;
        }
        const float* dbase = vecs + (size_t)pid * (DLN * HD);

        f32x4 acc[2][4] = {};
#pragma unroll
        for (int ks = 0; ks < 4; ++ks) {
#pragma unroll
            for (int nt = 0; nt < 4; ++nt) {
                const float* p = dbase + (nt * 16 + r16) * HD + ks * 32 + kb * 8;
                float4 x0 = *(const float4*)p;
                float4 x1 = *(const float4*)(p + 4);
                bf16x8 bh = cvt8(x0, x1);
#pragma unroll
                for (int m = 0; m < 2; ++m)
                    acc[m][nt] = __builtin_amdgcn_mfma_f32_16x16x32_bf16(
                        qf[m][ks], bh, acc[m][nt], 0, 0, 0);
            }
        }

        // Max over d: elementwise over the 4 n-tiles, then over lanes l&15.
        float s = 0.f;
#pragma unroll
        for (int m = 0; m < 2; ++m) {
#pragma unroll
            for (int r = 0; r < 4; ++r) {
                float x = fmaxf(fmaxf(acc[m][0][r], acc[m][1][r]),
                                fmaxf(acc[m][2][r], acc[m][3][r]));
                x = fmaxf(x, __shfl_xor(x, 1));
                x = fmaxf(x, __shfl_xor(x, 2));
                x = fmaxf(x, __shfl_xor(x, 4));
                x = fmaxf(x, __shfl_xor(x, 8));
                s += x;                              // row-max for q=(m*16+kb*4+r)
            }
        }
        // Sum over the 4 kb-groups -> all 32 q rows.
        s += __shfl_xor(s, 16);
        s += __shfl_xor(s, 32);
        if (lane == 0) scores[b * NC + n] = s * (1.0f / 32.0f);
    }
}

// ---------------------------------------------------------------------------
// K3a: per-row full bitonic sort of (f32 score desc, idx asc); keep top RK.
// ---------------------------------------------------------------------------
__global__ __launch_bounds__(1024) void k_select(
    const float* __restrict__ scores, int* __restrict__ sel)
{
    const int b = blockIdx.x;
    const int t = threadIdx.x;
    __shared__ float ss[NC];
    __shared__ int   si[NC];

    ss[t] = scores[b * NC + t];
    si[t] = t;
    __syncthreads();

    for (int k2 = 2; k2 <= NC; k2 <<= 1) {
        for (int j = k2 >> 1; j > 0; j >>= 1) {
            int ixj = t ^ j;
            if (ixj > t) {
                float as = ss[t], bs = ss[ixj];
                int   ai = si[t], bi = si[ixj];
                bool a_first = (as > bs) || (as == bs && ai < bi);
                bool desc = ((t & k2) == 0);
                if (desc ? !a_first : a_first) { ss[t] = bs; si[t] = bi; ss[ixj] = as; si[ixj] = ai; }
            }
            __syncthreads();
        }
    }
    if (t < RK) sel[b * RK + t] = si[t];
}

// ---------------------------------------------------------------------------
// K3b: exact f64 rescore of the RK selected per row — R1-proven kernel
// verbatim (one-chunk 64-row LDS tile, f32 q loads, f64 accumulate). This
// exact structure bit-matched the np reference and ran ~72 us at this grid.
// ---------------------------------------------------------------------------
#define DPAD (HD + 4)

__global__ __launch_bounds__(256) void k_rescore_f64(
    const float* __restrict__ q,     // [BB][QL][HD]
    const float* __restrict__ vecs,  // [n_docs][DLN][HD]
    const int* __restrict__ pids,    // [BB][NC]
    const int* __restrict__ sel,     // [BB][RK]
    double* __restrict__ resc)       // [BB][RK]
{
    const int r = blockIdx.x, b = blockIdx.y;
    const int t = threadIdx.x;
    const int n = sel[b * RK + r];
    const int pid = pids[b * NC + n];
    if (pid < 0) {
        if (t == 0) resc[b * RK + r] = -__builtin_inf();
        return;
    }

    __shared__ float sdoc[DLN][DPAD];
    __shared__ double red[4][16][2];

    {
        const float4* src = (const float4*)(vecs + (size_t)pid * DLN * HD);
        for (int i = t; i < DLN * HD / 4; i += 256) {
            float4 v = src[i];
            int d  = i >> 5;
            int h4 = (i & 31) << 2;
            *(float4*)&sdoc[d][h4] = v;
        }
    }
    __syncthreads();

    const int tq = t & 15;
    const int td = t >> 4;
    const float* qb = q + ((size_t)b * QL + tq * 2) * HD;

    double acc[2][4] = {};
    for (int h = 0; h < HD; h += 4) {
        float4 a0 = *(const float4*)(qb + h);
        float4 a1 = *(const float4*)(qb + HD + h);
        float4 bv[4];
#pragma unroll
        for (int j = 0; j < 4; ++j)
            bv[j] = *(const float4*)&sdoc[td * 4 + j][h];
#pragma unroll
        for (int j = 0; j < 4; ++j) {
            acc[0][j] += (double)a0.x * bv[j].x + (double)a0.y * bv[j].y
                       + (double)a0.z * bv[j].z + (double)a0.w * bv[j].w;
            acc[1][j] += (double)a1.x * bv[j].x + (double)a1.y * bv[j].y
                       + (double)a1.z * bv[j].z + (double)a1.w * bv[j].w;
        }
    }

    double m0 = fmax(fmax(acc[0][0], acc[0][1]), fmax(acc[0][2], acc[0][3]));
    double m1 = fmax(fmax(acc[1][0], acc[1][1]), fmax(acc[1][2], acc[1][3]));

    m0 = fmax(m0, __shfl_xor(m0, 16)); m1 = fmax(m1, __shfl_xor(m1, 16));
    m0 = fmax(m0, __shfl_xor(m0, 32)); m1 = fmax(m1, __shfl_xor(m1, 32));

    const int wave = t >> 6;
    if ((t & 63) < 16) { red[wave][tq][0] = m0; red[wave][tq][1] = m1; }
    __syncthreads();

    if (t < 32) {
        int g = t >> 1, i = t & 1;
        double v = fmax(fmax(red[0][g][i], red[1][g][i]),
                        fmax(red[2][g][i], red[3][g][i]));
        v += __shfl_xor(v, 1);
        v += __shfl_xor(v, 2);
        v += __shfl_xor(v, 4);
        v += __shfl_xor(v, 8);
        v += __shfl_xor(v, 16);
        if (t == 0) resc[b * RK + r] = v * (1.0 / 32.0);
    }
}

// ---------------------------------------------------------------------------
// K3c: sort the RK rescored candidates by (f64 score desc, idx asc); emit k.
// ---------------------------------------------------------------------------
__global__ __launch_bounds__(RK) void k_final(
    const double* __restrict__ resc, const int* __restrict__ sel,
    const int* __restrict__ pids, float* __restrict__ out, int k)
{
    const int b = blockIdx.x;
    const int t = threadIdx.x;
    __shared__ double ss[RK];
    __shared__ int    sn[RK];

    ss[t] = resc[b * RK + t];
    sn[t] = sel[b * RK + t];
    __syncthreads();

    for (int k2 = 2; k2 <= RK; k2 <<= 1) {
        for (int j = k2 >> 1; j > 0; j >>= 1) {
            int ixj = t ^ j;
            if (ixj > t) {
                double as = ss[t], bs = ss[ixj];
                int    ai = sn[t], bi = sn[ixj];
                bool a_first = (as > bs) || (as == bs && ai < bi);
                bool desc = ((t & k2) == 0);
                if (desc ? !a_first : a_first) { ss[t] = bs; sn[t] = bi; ss[ixj] = as; sn[ixj] = ai; }
            }
            __syncthreads();
        }
    }

    if (t < k) {
        out[b * k + t]          = (float)pids[b * NC + sn[t]];  // top_pids
        out[BB * k + b * k + t] = (float)ss[t];                 // top_scores
    }
}

// ---------------------------------------------------------------------------
extern "C" void kernel_launch(void* const* d_in, const int* in_sizes, int n_in,
                              void* d_out, int out_size, void* d_ws, size_t ws_size,
                              hipStream_t stream)
{
    const float* q_vectors = (const float*)d_in[0];   // [16][32][128] f32
    const int*   topk_idx  = (const int*)d_in[1];     // [16][1024] i32
    const float* vectors   = (const float*)d_in[2];   // [20000][64][128] f32
    const int*   emb2pid   = (const int*)d_in[3];     // [1280000] i32

    const int n_emb  = in_sizes[3];
    const int n_docs = in_sizes[2] / (DLN * HD);
    const int k      = out_size / (2 * BB);           // 100

    char* ws = (char*)d_ws;
    int*    pids_ws   = (int*)ws;      ws += BB * NC * sizeof(int);      // 64 KB
    float*  scores_ws = (float*)ws;    ws += BB * NC * sizeof(float);    // 64 KB
    int*    sel_ws    = (int*)ws;      ws += BB * RK * sizeof(int);      // 8 KB
    double* resc_ws   = (double*)ws;   ws += BB * RK * sizeof(double);   // 16 KB
    unsigned short* qhi_ws = (unsigned short*)ws;                        // 128 KB

    k_qprep<<<dim3(BB * QL * HD / 256), dim3(256), 0, stream>>>(
        q_vectors, qhi_ws);

    k_gather_sort_dedup<<<dim3(BB), dim3(NC), 0, stream>>>(
        topk_idx, emb2pid, n_emb, n_docs, pids_ws);

    k_screen_mfma<<<dim3(BB * NC / (4 * NPW)), dim3(256), 0, stream>>>(
        qhi_ws, vectors, pids_ws, scores_ws);

    k_select<<<dim3(BB), dim3(NC), 0, stream>>>(scores_ws, sel_ws);

    k_rescore_f64<<<dim3(RK, BB), dim3(256), 0, stream>>>(
        q_vectors, vectors, pids_ws, sel_ws, resc_ws);

    k_final<<<dim3(BB), dim3(RK), 0, stream>>>(
        resc_ws, sel_ws, pids_ws, (float*)d_out, k);
}